// Round 3
// baseline (553.032 us; speedup 1.0000x reference)
//
#include <hip/hip_runtime.h>

#define NN 256
#define XD 256
#define ED 128

typedef __attribute__((ext_vector_type(8))) short short8;
typedef __attribute__((ext_vector_type(4))) float f32x4;
typedef __attribute__((ext_vector_type(2))) unsigned int uint2v;

__device__ __forceinline__ unsigned short f2bf(float f) {
    unsigned u = __builtin_bit_cast(unsigned, f);
    u += 0x7FFF + ((u >> 16) & 1);
    return (unsigned short)(u >> 16);
}

// native packed f32->bf16 (RNE), 1 instr per 2 floats
__device__ __forceinline__ unsigned cvtpk(float lo, float hi) {
    unsigned r;
    asm("v_cvt_pk_bf16_f32 %0, %1, %2" : "=v"(r) : "v"(lo), "v"(hi));
    return r;
}

#define MFMA16(a, b, c) __builtin_amdgcn_mfma_f32_16x16x32_bf16(a, b, c, 0, 0, 0)

// ---------------------------------------------------------------------------
// Weight prep: transpose + bf16-convert all 7 weights to [n][k] layout.
// ---------------------------------------------------------------------------
__global__ __launch_bounds__(256) void wprep_kernel(
    const float* __restrict__ Wq, const float* __restrict__ Wk,
    const float* __restrict__ Wv, const float* __restrict__ Wxo,
    const float* __restrict__ Wem, const float* __restrict__ Wea,
    const float* __restrict__ Weo,
    short* __restrict__ WqT, short* __restrict__ WkT,
    short* __restrict__ WvT, short* __restrict__ WxoT,
    short* __restrict__ WemT, short* __restrict__ WeaT,
    short* __restrict__ WeoT)
{
    __shared__ float sT[32][33];
    int blk = blockIdx.x;
    const float* src; short* dst; int din, dout, tile;
    if (blk < 256) {
        int m = blk >> 6; tile = blk & 63; din = 256; dout = 256;
        src = m == 0 ? Wq : (m == 1 ? Wk : (m == 2 ? Wv : Wxo));
        dst = m == 0 ? WqT : (m == 1 ? WkT : (m == 2 ? WvT : WxoT));
    } else if (blk < 320) {
        int m = (blk - 256) >> 5; tile = (blk - 256) & 31; din = 128; dout = 256;
        src = m == 0 ? Wem : Wea; dst = m == 0 ? WemT : WeaT;
    } else {
        tile = blk - 320; din = 256; dout = 128;
        src = Weo; dst = WeoT;
    }
    int ksh = (din == 256) ? 3 : 2;
    int kt = tile & ((1 << ksh) - 1);
    int nt = tile >> ksh;
    int c = threadIdx.x & 31, rbase = threadIdx.x >> 5;
    #pragma unroll
    for (int p = 0; p < 4; ++p) {
        int r = rbase + p * 8;
        sT[r][c] = src[(kt * 32 + r) * dout + nt * 32 + c];
    }
    __syncthreads();
    #pragma unroll
    for (int p = 0; p < 4; ++p) {
        int r = rbase + p * 8;
        dst[(nt * 32 + r) * din + kt * 32 + c] = (short)f2bf(sT[c][r]);
    }
}

// ---------------------------------------------------------------------------
// Merged projections. blk<32: Q/K (16 mtiles x 2 mats). blk>=32: V + V@Wxo.
// Q row-major fp32 pre-scaled by 1/sqrt(32); K row-major Ks[b*N+j][c].
// ---------------------------------------------------------------------------
__global__ __launch_bounds__(512) void proj_all_kernel(
    const float* __restrict__ x,
    const short* __restrict__ WqT, const short* __restrict__ WkT,
    const short* __restrict__ WvT, const short* __restrict__ WxoT,
    const float* __restrict__ bq, const float* __restrict__ bk,
    const float* __restrict__ bv, const float* __restrict__ bxo,
    float* __restrict__ Qs, float* __restrict__ Ks, float* __restrict__ outX)
{
    __shared__ unsigned short sX[64 * 264];
    __shared__ unsigned short sV[64 * 264];
    const int blk = blockIdx.x;
    const bool isvx = blk >= 32;
    const int mtile = isvx ? (blk - 32) : (blk >> 1);
    const int tid = threadIdx.x, wave = tid >> 6, lane = tid & 63;
    const int quad = lane >> 4, l16 = lane & 15;

    {   // stage x tile fp32 -> bf16
        const float4* src4 = (const float4*)(x + (size_t)mtile * 64 * XD);
        #pragma unroll
        for (int it = 0; it < 8; ++it) {
            int idx4 = tid + it * 512;
            float4 v = src4[idx4];
            int elem = idx4 * 4, row = elem >> 8, col = elem & 255;
            uint2v p; p.x = cvtpk(v.x, v.y); p.y = cvtpk(v.z, v.w);
            *(uint2v*)&sX[row * 264 + col] = p;
        }
    }
    __syncthreads();

    const int c0 = wave * 32;

    if (!isvx) {
        const int mat  = blk & 1;
        const short* WT   = mat ? WkT : WqT;
        const float* bias = mat ? bk : bq;
        const float scale = mat ? 1.0f : 0.17677669529663687f;
        float* out        = mat ? Ks : Qs;
        f32x4 acc[4][2] = {};
        for (int ks = 0; ks < 8; ++ks) {
            short8 bfrag[2];
            #pragma unroll
            for (int ct = 0; ct < 2; ++ct)
                bfrag[ct] = *(const short8*)&WT[(c0 + ct * 16 + l16) * 256 + ks * 32 + quad * 8];
            #pragma unroll
            for (int mt = 0; mt < 4; ++mt) {
                short8 a = *(const short8*)&sX[(mt * 16 + l16) * 264 + ks * 32 + quad * 8];
                acc[mt][0] = MFMA16(a, bfrag[0], acc[mt][0]);
                acc[mt][1] = MFMA16(a, bfrag[1], acc[mt][1]);
            }
        }
        #pragma unroll
        for (int mt = 0; mt < 4; ++mt)
            #pragma unroll
            for (int ct = 0; ct < 2; ++ct) {
                int cc = c0 + ct * 16 + l16;
                float bb = bias[cc];
                #pragma unroll
                for (int r = 0; r < 4; ++r)
                    out[(size_t)(mtile * 64 + mt * 16 + quad * 4 + r) * 256 + cc] =
                        (acc[mt][ct][r] + bb) * scale;
            }
    } else {
        f32x4 acc[4][2] = {};
        for (int ks = 0; ks < 8; ++ks) {
            short8 bfrag[2];
            #pragma unroll
            for (int ct = 0; ct < 2; ++ct)
                bfrag[ct] = *(const short8*)&WvT[(c0 + ct * 16 + l16) * 256 + ks * 32 + quad * 8];
            #pragma unroll
            for (int mt = 0; mt < 4; ++mt) {
                short8 a = *(const short8*)&sX[(mt * 16 + l16) * 264 + ks * 32 + quad * 8];
                acc[mt][0] = MFMA16(a, bfrag[0], acc[mt][0]);
                acc[mt][1] = MFMA16(a, bfrag[1], acc[mt][1]);
            }
        }
        #pragma unroll
        for (int mt = 0; mt < 4; ++mt)
            #pragma unroll
            for (int ct = 0; ct < 2; ++ct) {
                int cc = c0 + ct * 16 + l16;
                float bb = bv[cc];
                #pragma unroll
                for (int r = 0; r < 4; ++r)
                    sV[(mt * 16 + quad * 4 + r) * 264 + cc] = f2bf(acc[mt][ct][r] + bb);
            }
        __syncthreads();
        f32x4 acc2[4][2] = {};
        for (int ks = 0; ks < 8; ++ks) {
            short8 bfrag[2];
            #pragma unroll
            for (int ct = 0; ct < 2; ++ct)
                bfrag[ct] = *(const short8*)&WxoT[(c0 + ct * 16 + l16) * 256 + ks * 32 + quad * 8];
            #pragma unroll
            for (int mt = 0; mt < 4; ++mt) {
                short8 a = *(const short8*)&sV[(mt * 16 + l16) * 264 + ks * 32 + quad * 8];
                acc2[mt][0] = MFMA16(a, bfrag[0], acc2[mt][0]);
                acc2[mt][1] = MFMA16(a, bfrag[1], acc2[mt][1]);
            }
        }
        #pragma unroll
        for (int mt = 0; mt < 4; ++mt)
            #pragma unroll
            for (int ct = 0; ct < 2; ++ct) {
                int cc = c0 + ct * 16 + l16;
                float bb = bxo[cc];
                #pragma unroll
                for (int r = 0; r < 4; ++r)
                    outX[(size_t)(mtile * 64 + mt * 16 + quad * 4 + r) * 256 + cc] =
                        acc2[mt][ct][r] + bb;
            }
    }
}

// ---------------------------------------------------------------------------
// Fused edge kernel v6: persistent (b,i) block (1024 blocks), software-
// pipelined loop over 4 j-subtiles (64 j each).
//   t-loop: ef<-sE; GEMM1->sY; barrier; issue e-loads(t+1); GEMM2->stores;
//           cvt+write sE(t+1); barrier.
//   - e-load latency hides under GEMM2 (T14 issue-early / write-late).
//   - GEMM2 repartition: wave owns (o-half 64 x j-half 32) -> 16 ds_read_b128
//     (was 32) at same MFMA count.
//   - v5's verified tile math / conflict-free pitches (140 / 268) unchanged.
// ---------------------------------------------------------------------------
__global__ __launch_bounds__(256, 3) void fused_edge_kernel(
    const float* __restrict__ e, const float* __restrict__ Qs,
    const float* __restrict__ Ks, const short* __restrict__ WemT,
    const short* __restrict__ WeaT, const short* __restrict__ WeoT,
    const float* __restrict__ bem, const float* __restrict__ bea,
    const float* __restrict__ beo, float* __restrict__ outE)
{
    __shared__ unsigned short sE[64 * 140];   // e tile bf16, pitch 140
    __shared__ unsigned short sY[64 * 268];   // Y tile bf16, pitch 268

    const int blk  = blockIdx.x;              // 1024 = b*256 + i
    const int i    = blk & 255;
    const int b    = blk >> 8;
    const int tid  = threadIdx.x;
    const int wave = tid >> 6;
    const int lane = tid & 63;
    const int quad = lane >> 4;
    const int l16  = lane & 15;

    const float4* ebase = (const float4*)(e + (size_t)((b * NN + i) * NN) * ED);

    // ---- prologue: stage e subtile t=0
    {
        float4 ev[8];
        #pragma unroll
        for (int it = 0; it < 8; ++it) ev[it] = ebase[tid + it * 256];
        #pragma unroll
        for (int it = 0; it < 8; ++it) {
            int idx4 = tid + it * 256;
            int row = idx4 >> 5, col = (idx4 & 31) * 4;
            uint2v p; p.x = cvtpk(ev[it].x, ev[it].y); p.y = cvtpk(ev[it].z, ev[it].w);
            *(uint2v*)&sE[row * 140 + col] = p;
        }
    }
    __syncthreads();

    const float* Qrow = Qs + (size_t)(b * NN + i) * XD;
    const int cW = wave * 64;                 // GEMM1: wave's 64-c window
    const int oH = (wave & 1) * 64;           // GEMM2: wave's o-half
    const int jH = (wave >> 1) * 2;           // GEMM2: wave's j-half (2 jT)

    #pragma unroll 1
    for (int t = 0; t < 4; ++t) {
        const int j0 = t * 64;

        // ---- e-fragments register-resident (16 ds_read_b128)
        short8 efr[4][4];
        #pragma unroll
        for (int jT = 0; jT < 4; ++jT)
            #pragma unroll
            for (int ks = 0; ks < 4; ++ks)
                efr[jT][ks] = *(const short8*)&sE[(jT * 16 + l16) * 140 + ks * 32 + quad * 8];

        // ---- GEMM1 (swapped) + combine -> sY
        #pragma unroll
        for (int cT = 0; cT < 4; ++cT) {
            const int c0 = cW + cT * 16;
            const int cq = c0 + quad * 4;
            f32x4 q4  = *(const f32x4*)&Qrow[cq];
            f32x4 bm4 = *(const f32x4*)&bem[cq] + 1.0f;
            f32x4 ba4 = *(const f32x4*)&bea[cq];
            f32x4 k4[4];
            #pragma unroll
            for (int jT = 0; jT < 4; ++jT)
                k4[jT] = *(const f32x4*)&Ks[(size_t)(b * NN + j0 + jT * 16 + l16) * XD + cq];

            f32x4 a1[4] = {}, a2[4] = {};
            #pragma unroll
            for (int ks = 0; ks < 4; ++ks) {
                short8 wa = *(const short8*)&WemT[(c0 + l16) * 128 + ks * 32 + quad * 8];
                short8 wb = *(const short8*)&WeaT[(c0 + l16) * 128 + ks * 32 + quad * 8];
                #pragma unroll
                for (int jT = 0; jT < 4; ++jT) {
                    a1[jT] = MFMA16(wa, efr[jT][ks], a1[jT]);
                    a2[jT] = MFMA16(wb, efr[jT][ks], a2[jT]);
                }
            }
            #pragma unroll
            for (int jT = 0; jT < 4; ++jT) {
                f32x4 y = q4 * k4[jT] * (a1[jT] + bm4) + (a2[jT] + ba4);
                uint2v p; p.x = cvtpk(y[0], y[1]); p.y = cvtpk(y[2], y[3]);
                *(uint2v*)&sY[(jT * 16 + l16) * 268 + cq] = p;
            }
        }
        __syncthreads();   // sY ready; sE fully consumed (efr in regs)

        // ---- issue e-loads for t+1 (latency hides under GEMM2)
        float4 ev[8];
        if (t < 3) {
            #pragma unroll
            for (int it = 0; it < 8; ++it)
                ev[it] = ebase[(t + 1) * 2048 + tid + it * 256];
        }

        // ---- GEMM2 (swapped, repartitioned): wave = (o-half, j-half)
        f32x4 acc[4][2] = {};
        #pragma unroll
        for (int ks = 0; ks < 8; ++ks) {
            short8 wo[4];
            #pragma unroll
            for (int oT = 0; oT < 4; ++oT)
                wo[oT] = *(const short8*)&WeoT[(oH + oT * 16 + l16) * 256 + ks * 32 + quad * 8];
            #pragma unroll
            for (int jt = 0; jt < 2; ++jt) {
                short8 yb = *(const short8*)&sY[((jH + jt) * 16 + l16) * 268 + ks * 32 + quad * 8];
                #pragma unroll
                for (int oT = 0; oT < 4; ++oT)
                    acc[oT][jt] = MFMA16(wo[oT], yb, acc[oT][jt]);
            }
        }

        // ---- write sE for t+1 (waits only on ev loads)
        if (t < 3) {
            #pragma unroll
            for (int it = 0; it < 8; ++it) {
                int idx4 = tid + it * 256;
                int row = idx4 >> 5, col = (idx4 & 31) * 4;
                uint2v p; p.x = cvtpk(ev[it].x, ev[it].y); p.y = cvtpk(ev[it].z, ev[it].w);
                *(uint2v*)&sE[row * 140 + col] = p;
            }
        }

        // ---- store newE^T block
        float* outBase = outE + (size_t)((b * NN + i) * NN + j0) * ED;
        #pragma unroll
        for (int oT = 0; oT < 4; ++oT) {
            const int oq = oH + oT * 16 + quad * 4;
            f32x4 bo4 = *(const f32x4*)&beo[oq];
            #pragma unroll
            for (int jt = 0; jt < 2; ++jt) {
                f32x4 st = acc[oT][jt] + bo4;
                *(f32x4*)&outBase[(size_t)((jH + jt) * 16 + l16) * ED + oq] = st;
            }
        }
        __syncthreads();   // sE(t+1) visible; sY consumed
    }
}

extern "C" void kernel_launch(void* const* d_in, const int* in_sizes, int n_in,
                              void* d_out, int out_size, void* d_ws, size_t ws_size,
                              hipStream_t stream)
{
    const float* x   = (const float*)d_in[0];
    const float* e   = (const float*)d_in[1];
    const float* Wq  = (const float*)d_in[2];
    const float* bq  = (const float*)d_in[3];
    const float* Wk  = (const float*)d_in[4];
    const float* bk  = (const float*)d_in[5];
    const float* Wv  = (const float*)d_in[6];
    const float* bv  = (const float*)d_in[7];
    const float* Wem = (const float*)d_in[8];
    const float* bem = (const float*)d_in[9];
    const float* Wea = (const float*)d_in[10];
    const float* bea = (const float*)d_in[11];
    const float* Wxo = (const float*)d_in[12];
    const float* bxo = (const float*)d_in[13];
    const float* Weo = (const float*)d_in[14];
    const float* beo = (const float*)d_in[15];

    float* outX = (float*)d_out;                 // newX: 262144 f32
    float* outE = (float*)d_out + 262144;        // newE: 33554432 f32

    float* Qs   = (float*)d_ws;                  // [1024][256] f32 (scaled)
    float* Ks   = Qs + 262144;                   // [1024][256] f32 row-major
    short* WqT  = (short*)(Ks + 262144);         // [256][256] bf16
    short* WkT  = WqT + 65536;
    short* WvT  = WkT + 65536;
    short* WxoT = WvT + 65536;
    short* WemT = WxoT + 65536;                  // [256][128] bf16
    short* WeaT = WemT + 32768;
    short* WeoT = WeaT + 32768;                  // [128][256] bf16

    hipLaunchKernelGGL(wprep_kernel, dim3(352), dim3(256), 0, stream,
                       Wq, Wk, Wv, Wxo, Wem, Wea, Weo,
                       WqT, WkT, WvT, WxoT, WemT, WeaT, WeoT);
    hipLaunchKernelGGL(proj_all_kernel, dim3(48), dim3(512), 0, stream,
                       x, WqT, WkT, WvT, WxoT, bq, bk, bv, bxo, Qs, Ks, outX);
    hipLaunchKernelGGL(fused_edge_kernel, dim3(1024), dim3(256), 0, stream,
                       e, Qs, Ks, WemT, WeaT, WeoT, bem, bea, beo, outE);
}

// Round 4
// 399.039 us; speedup vs baseline: 1.3859x; 1.3859x over previous
//
#include <hip/hip_runtime.h>

#define NN 256
#define XD 256
#define ED 128

typedef __attribute__((ext_vector_type(8))) short short8;
typedef __attribute__((ext_vector_type(4))) float f32x4;
typedef __attribute__((ext_vector_type(2))) unsigned int uint2v;

__device__ __forceinline__ unsigned short f2bf(float f) {
    unsigned u = __builtin_bit_cast(unsigned, f);
    u += 0x7FFF + ((u >> 16) & 1);
    return (unsigned short)(u >> 16);
}

// native packed f32->bf16 (RNE), 1 instr per 2 floats
__device__ __forceinline__ unsigned cvtpk(float lo, float hi) {
    unsigned r;
    asm("v_cvt_pk_bf16_f32 %0, %1, %2" : "=v"(r) : "v"(lo), "v"(hi));
    return r;
}

#define MFMA16(a, b, c) __builtin_amdgcn_mfma_f32_16x16x32_bf16(a, b, c, 0, 0, 0)

// ---------------------------------------------------------------------------
// Weight prep: transpose + bf16-convert all 7 weights to [n][k] layout.
// ---------------------------------------------------------------------------
__global__ __launch_bounds__(256) void wprep_kernel(
    const float* __restrict__ Wq, const float* __restrict__ Wk,
    const float* __restrict__ Wv, const float* __restrict__ Wxo,
    const float* __restrict__ Wem, const float* __restrict__ Wea,
    const float* __restrict__ Weo,
    short* __restrict__ WqT, short* __restrict__ WkT,
    short* __restrict__ WvT, short* __restrict__ WxoT,
    short* __restrict__ WemT, short* __restrict__ WeaT,
    short* __restrict__ WeoT)
{
    __shared__ float sT[32][33];
    int blk = blockIdx.x;
    const float* src; short* dst; int din, dout, tile;
    if (blk < 256) {
        int m = blk >> 6; tile = blk & 63; din = 256; dout = 256;
        src = m == 0 ? Wq : (m == 1 ? Wk : (m == 2 ? Wv : Wxo));
        dst = m == 0 ? WqT : (m == 1 ? WkT : (m == 2 ? WvT : WxoT));
    } else if (blk < 320) {
        int m = (blk - 256) >> 5; tile = (blk - 256) & 31; din = 128; dout = 256;
        src = m == 0 ? Wem : Wea; dst = m == 0 ? WemT : WeaT;
    } else {
        tile = blk - 320; din = 256; dout = 128;
        src = Weo; dst = WeoT;
    }
    int ksh = (din == 256) ? 3 : 2;
    int kt = tile & ((1 << ksh) - 1);
    int nt = tile >> ksh;
    int c = threadIdx.x & 31, rbase = threadIdx.x >> 5;
    #pragma unroll
    for (int p = 0; p < 4; ++p) {
        int r = rbase + p * 8;
        sT[r][c] = src[(kt * 32 + r) * dout + nt * 32 + c];
    }
    __syncthreads();
    #pragma unroll
    for (int p = 0; p < 4; ++p) {
        int r = rbase + p * 8;
        dst[(nt * 32 + r) * din + kt * 32 + c] = (short)f2bf(sT[c][r]);
    }
}

// ---------------------------------------------------------------------------
// Merged projections. blk<32: Q/K (16 mtiles x 2 mats). blk>=32: V + V@Wxo.
// Q row-major fp32 pre-scaled by 1/sqrt(32); K row-major Ks[b*N+j][c].
// ---------------------------------------------------------------------------
__global__ __launch_bounds__(512) void proj_all_kernel(
    const float* __restrict__ x,
    const short* __restrict__ WqT, const short* __restrict__ WkT,
    const short* __restrict__ WvT, const short* __restrict__ WxoT,
    const float* __restrict__ bq, const float* __restrict__ bk,
    const float* __restrict__ bv, const float* __restrict__ bxo,
    float* __restrict__ Qs, float* __restrict__ Ks, float* __restrict__ outX)
{
    __shared__ unsigned short sX[64 * 264];
    __shared__ unsigned short sV[64 * 264];
    const int blk = blockIdx.x;
    const bool isvx = blk >= 32;
    const int mtile = isvx ? (blk - 32) : (blk >> 1);
    const int tid = threadIdx.x, wave = tid >> 6, lane = tid & 63;
    const int quad = lane >> 4, l16 = lane & 15;

    {   // stage x tile fp32 -> bf16
        const float4* src4 = (const float4*)(x + (size_t)mtile * 64 * XD);
        #pragma unroll
        for (int it = 0; it < 8; ++it) {
            int idx4 = tid + it * 512;
            float4 v = src4[idx4];
            int elem = idx4 * 4, row = elem >> 8, col = elem & 255;
            uint2v p; p.x = cvtpk(v.x, v.y); p.y = cvtpk(v.z, v.w);
            *(uint2v*)&sX[row * 264 + col] = p;
        }
    }
    __syncthreads();

    const int c0 = wave * 32;

    if (!isvx) {
        const int mat  = blk & 1;
        const short* WT   = mat ? WkT : WqT;
        const float* bias = mat ? bk : bq;
        const float scale = mat ? 1.0f : 0.17677669529663687f;
        float* out        = mat ? Ks : Qs;
        f32x4 acc[4][2] = {};
        for (int ks = 0; ks < 8; ++ks) {
            short8 bfrag[2];
            #pragma unroll
            for (int ct = 0; ct < 2; ++ct)
                bfrag[ct] = *(const short8*)&WT[(c0 + ct * 16 + l16) * 256 + ks * 32 + quad * 8];
            #pragma unroll
            for (int mt = 0; mt < 4; ++mt) {
                short8 a = *(const short8*)&sX[(mt * 16 + l16) * 264 + ks * 32 + quad * 8];
                acc[mt][0] = MFMA16(a, bfrag[0], acc[mt][0]);
                acc[mt][1] = MFMA16(a, bfrag[1], acc[mt][1]);
            }
        }
        #pragma unroll
        for (int mt = 0; mt < 4; ++mt)
            #pragma unroll
            for (int ct = 0; ct < 2; ++ct) {
                int cc = c0 + ct * 16 + l16;
                float bb = bias[cc];
                #pragma unroll
                for (int r = 0; r < 4; ++r)
                    out[(size_t)(mtile * 64 + mt * 16 + quad * 4 + r) * 256 + cc] =
                        (acc[mt][ct][r] + bb) * scale;
            }
    } else {
        f32x4 acc[4][2] = {};
        for (int ks = 0; ks < 8; ++ks) {
            short8 bfrag[2];
            #pragma unroll
            for (int ct = 0; ct < 2; ++ct)
                bfrag[ct] = *(const short8*)&WvT[(c0 + ct * 16 + l16) * 256 + ks * 32 + quad * 8];
            #pragma unroll
            for (int mt = 0; mt < 4; ++mt) {
                short8 a = *(const short8*)&sX[(mt * 16 + l16) * 264 + ks * 32 + quad * 8];
                acc[mt][0] = MFMA16(a, bfrag[0], acc[mt][0]);
                acc[mt][1] = MFMA16(a, bfrag[1], acc[mt][1]);
            }
        }
        #pragma unroll
        for (int mt = 0; mt < 4; ++mt)
            #pragma unroll
            for (int ct = 0; ct < 2; ++ct) {
                int cc = c0 + ct * 16 + l16;
                float bb = bv[cc];
                #pragma unroll
                for (int r = 0; r < 4; ++r)
                    sV[(mt * 16 + quad * 4 + r) * 264 + cc] = f2bf(acc[mt][ct][r] + bb);
            }
        __syncthreads();
        f32x4 acc2[4][2] = {};
        for (int ks = 0; ks < 8; ++ks) {
            short8 bfrag[2];
            #pragma unroll
            for (int ct = 0; ct < 2; ++ct)
                bfrag[ct] = *(const short8*)&WxoT[(c0 + ct * 16 + l16) * 256 + ks * 32 + quad * 8];
            #pragma unroll
            for (int mt = 0; mt < 4; ++mt) {
                short8 a = *(const short8*)&sV[(mt * 16 + l16) * 264 + ks * 32 + quad * 8];
                acc2[mt][0] = MFMA16(a, bfrag[0], acc2[mt][0]);
                acc2[mt][1] = MFMA16(a, bfrag[1], acc2[mt][1]);
            }
        }
        #pragma unroll
        for (int mt = 0; mt < 4; ++mt)
            #pragma unroll
            for (int ct = 0; ct < 2; ++ct) {
                int cc = c0 + ct * 16 + l16;
                float bb = bxo[cc];
                #pragma unroll
                for (int r = 0; r < 4; ++r)
                    outX[(size_t)(mtile * 64 + mt * 16 + quad * 4 + r) * 256 + cc] =
                        acc2[mt][ct][r] + bb;
            }
    }
}

// ---------------------------------------------------------------------------
// Fused edge kernel v7: v5 tile math with split-k GEMM2 -> half-size sY.
//   LDS = sE[64x140] + sY[64x140] = 35.8 KB -> 4 blocks/CU (was 52.2 KB / 3).
//   Two phases p=0,1 over c-halves [0,128)/[128,256):
//     G1(phase p): wave owns 32-c window, writes sY local cols [0,128)
//     barrier; G2 accumulates ks in {4p..4p+3} into persistent acc[2][4]
//     barrier (p=0 only, before sY overwrite).
//   Per-wave load/MFMA totals identical to v5; pitches keep rowstride==24
//   (mod 128) -> the measured-0-conflict pattern. 4096 blocks, 256 thr.
// ---------------------------------------------------------------------------
__global__ __launch_bounds__(256, 4) void fused_edge_kernel(
    const float* __restrict__ e, const float* __restrict__ Qs,
    const float* __restrict__ Ks, const short* __restrict__ WemT,
    const short* __restrict__ WeaT, const short* __restrict__ WeoT,
    const float* __restrict__ bem, const float* __restrict__ bea,
    const float* __restrict__ beo, float* __restrict__ outE)
{
    __shared__ unsigned short sE[64 * 140];   // e tile bf16, pitch 140
    __shared__ unsigned short sY[64 * 140];   // Y half-tile bf16, pitch 140

    const int blk  = blockIdx.x;              // 4096 blocks
    const int jq   = blk & 3;
    const int i    = (blk >> 2) & 255;
    const int b    = blk >> 10;
    const int j0   = jq * 64;
    const int tid  = threadIdx.x;
    const int wave = tid >> 6;
    const int lane = tid & 63;
    const int quad = lane >> 4;
    const int l16  = lane & 15;

    // ---- stage e tile [64 x 128]: batch loads, then convert+write
    {
        const float4* src4 = (const float4*)(e + (size_t)((b * NN + i) * NN + j0) * ED);
        float4 ev[8];
        #pragma unroll
        for (int it = 0; it < 8; ++it) ev[it] = src4[tid + it * 256];
        #pragma unroll
        for (int it = 0; it < 8; ++it) {
            int idx4 = tid + it * 256;
            int row = idx4 >> 5, col = (idx4 & 31) * 4;
            uint2v p; p.x = cvtpk(ev[it].x, ev[it].y); p.y = cvtpk(ev[it].z, ev[it].w);
            *(uint2v*)&sE[row * 140 + col] = p;
        }
    }
    __syncthreads();

    const float* Qrow = Qs + (size_t)(b * NN + i) * XD;
    const int oW = wave * 32;                 // GEMM2 o-window
    f32x4 acc[2][4] = {};                     // GEMM2 accum, persists phases

    #pragma unroll
    for (int p = 0; p < 2; ++p) {
        // ---- GEMM1 (swapped) for this c-half; wave owns 32-c window
        #pragma unroll
        for (int cT = 0; cT < 2; ++cT) {
            const int cl = wave * 32 + cT * 16;    // local col in [0,128)
            const int c0 = p * 128 + cl;           // global c
            const int cq = c0 + quad * 4;
            f32x4 q4  = *(const f32x4*)&Qrow[cq];
            f32x4 bm4 = *(const f32x4*)&bem[cq] + 1.0f;
            f32x4 ba4 = *(const f32x4*)&bea[cq];
            f32x4 k4[4];
            #pragma unroll
            for (int jT = 0; jT < 4; ++jT)
                k4[jT] = *(const f32x4*)&Ks[(size_t)(b * NN + j0 + jT * 16 + l16) * XD + cq];

            f32x4 a1[4] = {}, a2[4] = {};
            #pragma unroll
            for (int ks = 0; ks < 4; ++ks) {
                short8 wa = *(const short8*)&WemT[(c0 + l16) * 128 + ks * 32 + quad * 8];
                short8 wb = *(const short8*)&WeaT[(c0 + l16) * 128 + ks * 32 + quad * 8];
                #pragma unroll
                for (int jT = 0; jT < 4; ++jT) {
                    short8 ef = *(const short8*)&sE[(jT * 16 + l16) * 140 + ks * 32 + quad * 8];
                    a1[jT] = MFMA16(wa, ef, a1[jT]);
                    a2[jT] = MFMA16(wb, ef, a2[jT]);
                }
            }
            #pragma unroll
            for (int jT = 0; jT < 4; ++jT) {
                f32x4 y = q4 * k4[jT] * (a1[jT] + bm4) + (a2[jT] + ba4);
                uint2v pk; pk.x = cvtpk(y[0], y[1]); pk.y = cvtpk(y[2], y[3]);
                *(uint2v*)&sY[(jT * 16 + l16) * 140 + cl + quad * 4] = pk;
            }
        }
        __syncthreads();   // sY(half p) ready

        // ---- GEMM2 partial: accumulate k-range [p*128, p*128+128)
        #pragma unroll
        for (int ks = 0; ks < 4; ++ks) {
            short8 w0 = *(const short8*)&WeoT[(oW + l16) * 256 + (p * 4 + ks) * 32 + quad * 8];
            short8 w1 = *(const short8*)&WeoT[(oW + 16 + l16) * 256 + (p * 4 + ks) * 32 + quad * 8];
            #pragma unroll
            for (int jT = 0; jT < 4; ++jT) {
                short8 yb = *(const short8*)&sY[(jT * 16 + l16) * 140 + ks * 32 + quad * 8];
                acc[0][jT] = MFMA16(w0, yb, acc[0][jT]);
                acc[1][jT] = MFMA16(w1, yb, acc[1][jT]);
            }
        }
        if (p == 0) __syncthreads();   // sY consumed before overwrite
    }

    // ---- store newE^T block (float4 per lane)
    float* outBase = outE + (size_t)((b * NN + i) * NN + j0) * ED;
    #pragma unroll
    for (int oT = 0; oT < 2; ++oT) {
        const int oq = oW + oT * 16 + quad * 4;
        f32x4 bo4 = *(const f32x4*)&beo[oq];
        #pragma unroll
        for (int jT = 0; jT < 4; ++jT) {
            f32x4 st = acc[oT][jT] + bo4;
            *(f32x4*)&outBase[(size_t)(jT * 16 + l16) * ED + oq] = st;
        }
    }
}

extern "C" void kernel_launch(void* const* d_in, const int* in_sizes, int n_in,
                              void* d_out, int out_size, void* d_ws, size_t ws_size,
                              hipStream_t stream)
{
    const float* x   = (const float*)d_in[0];
    const float* e   = (const float*)d_in[1];
    const float* Wq  = (const float*)d_in[2];
    const float* bq  = (const float*)d_in[3];
    const float* Wk  = (const float*)d_in[4];
    const float* bk  = (const float*)d_in[5];
    const float* Wv  = (const float*)d_in[6];
    const float* bv  = (const float*)d_in[7];
    const float* Wem = (const float*)d_in[8];
    const float* bem = (const float*)d_in[9];
    const float* Wea = (const float*)d_in[10];
    const float* bea = (const float*)d_in[11];
    const float* Wxo = (const float*)d_in[12];
    const float* bxo = (const float*)d_in[13];
    const float* Weo = (const float*)d_in[14];
    const float* beo = (const float*)d_in[15];

    float* outX = (float*)d_out;                 // newX: 262144 f32
    float* outE = (float*)d_out + 262144;        // newE: 33554432 f32

    float* Qs   = (float*)d_ws;                  // [1024][256] f32 (scaled)
    float* Ks   = Qs + 262144;                   // [1024][256] f32 row-major
    short* WqT  = (short*)(Ks + 262144);         // [256][256] bf16
    short* WkT  = WqT + 65536;
    short* WvT  = WkT + 65536;
    short* WxoT = WvT + 65536;
    short* WemT = WxoT + 65536;                  // [256][128] bf16
    short* WeaT = WemT + 32768;
    short* WeoT = WeaT + 32768;                  // [128][256] bf16

    hipLaunchKernelGGL(wprep_kernel, dim3(352), dim3(256), 0, stream,
                       Wq, Wk, Wv, Wxo, Wem, Wea, Weo,
                       WqT, WkT, WvT, WxoT, WemT, WeaT, WeoT);
    hipLaunchKernelGGL(proj_all_kernel, dim3(48), dim3(512), 0, stream,
                       x, WqT, WkT, WvT, WxoT, bq, bk, bv, bxo, Qs, Ks, outX);
    hipLaunchKernelGGL(fused_edge_kernel, dim3(4096), dim3(256), 0, stream,
                       e, Qs, Ks, WemT, WeaT, WeoT, bem, bea, beo, outE);
}

// Round 5
// 365.973 us; speedup vs baseline: 1.5111x; 1.0904x over previous
//
#include <hip/hip_runtime.h>

#define NN 256
#define XD 256
#define ED 128

typedef __attribute__((ext_vector_type(8))) short short8;
typedef __attribute__((ext_vector_type(4))) float f32x4;

__device__ __forceinline__ unsigned short f2bf(float f) {
    unsigned u = __builtin_bit_cast(unsigned, f);
    u += 0x7FFF + ((u >> 16) & 1);
    return (unsigned short)(u >> 16);
}

#define MFMA16(a, b, c) __builtin_amdgcn_mfma_f32_16x16x32_bf16(a, b, c, 0, 0, 0)

// ---------------------------------------------------------------------------
// Weight prep: transpose + bf16-convert all 7 weights to [n][k] layout.
// ---------------------------------------------------------------------------
__global__ __launch_bounds__(256) void wprep_kernel(
    const float* __restrict__ Wq, const float* __restrict__ Wk,
    const float* __restrict__ Wv, const float* __restrict__ Wxo,
    const float* __restrict__ Wem, const float* __restrict__ Wea,
    const float* __restrict__ Weo,
    short* __restrict__ WqT, short* __restrict__ WkT,
    short* __restrict__ WvT, short* __restrict__ WxoT,
    short* __restrict__ WemT, short* __restrict__ WeaT,
    short* __restrict__ WeoT)
{
    __shared__ float sT[32][33];
    int blk = blockIdx.x;
    const float* src; short* dst; int din, dout, tile;
    if (blk < 256) {
        int m = blk >> 6; tile = blk & 63; din = 256; dout = 256;
        src = m == 0 ? Wq : (m == 1 ? Wk : (m == 2 ? Wv : Wxo));
        dst = m == 0 ? WqT : (m == 1 ? WkT : (m == 2 ? WvT : WxoT));
    } else if (blk < 320) {
        int m = (blk - 256) >> 5; tile = (blk - 256) & 31; din = 128; dout = 256;
        src = m == 0 ? Wem : Wea; dst = m == 0 ? WemT : WeaT;
    } else {
        tile = blk - 320; din = 256; dout = 128;
        src = Weo; dst = WeoT;
    }
    int ksh = (din == 256) ? 3 : 2;
    int kt = tile & ((1 << ksh) - 1);
    int nt = tile >> ksh;
    int c = threadIdx.x & 31, rbase = threadIdx.x >> 5;
    #pragma unroll
    for (int p = 0; p < 4; ++p) {
        int r = rbase + p * 8;
        sT[r][c] = src[(kt * 32 + r) * dout + nt * 32 + c];
    }
    __syncthreads();
    #pragma unroll
    for (int p = 0; p < 4; ++p) {
        int r = rbase + p * 8;
        dst[(nt * 32 + r) * din + kt * 32 + c] = (short)f2bf(sT[c][r]);
    }
}

// ---------------------------------------------------------------------------
// Q/K projection via MFMA. grid = 16 m-tiles (64 rows) x 2 mats = 32 blocks.
// Q row-major fp32 pre-scaled by 1/sqrt(32); K stored transposed KT[b][c][j].
// ---------------------------------------------------------------------------
__global__ __launch_bounds__(512) void proj_qk_kernel(
    const float* __restrict__ x, const short* __restrict__ WqT,
    const short* __restrict__ WkT, const float* __restrict__ bq,
    const float* __restrict__ bk, float* __restrict__ Qs,
    float* __restrict__ KT)
{
    __shared__ unsigned short sX[64 * 264];
    const int blk = blockIdx.x;
    const int mtile = blk >> 1;   // 0..15 (64-row tile of the 1024 rows)
    const int mat   = blk & 1;    // 0: Q, 1: K
    const int tid = threadIdx.x, wave = tid >> 6, lane = tid & 63;
    const int quad = lane >> 4, l16 = lane & 15;

    {   // stage x tile fp32 -> bf16
        const float4* src4 = (const float4*)(x + (size_t)mtile * 64 * XD);
        #pragma unroll
        for (int it = 0; it < 8; ++it) {
            int idx4 = tid + it * 512;
            float4 v = src4[idx4];
            int elem = idx4 * 4, row = elem >> 8, col = elem & 255;
            short4 p = make_short4((short)f2bf(v.x), (short)f2bf(v.y),
                                   (short)f2bf(v.z), (short)f2bf(v.w));
            *(short4*)&sX[row * 264 + col] = p;
        }
    }
    __syncthreads();

    const short* WT   = mat ? WkT : WqT;
    const float* bias = mat ? bk : bq;
    const int c0 = wave * 32;

    f32x4 acc[4][2] = {};
    for (int ks = 0; ks < 8; ++ks) {
        short8 bfrag[2];
        #pragma unroll
        for (int ct = 0; ct < 2; ++ct)
            bfrag[ct] = *(const short8*)&WT[(c0 + ct * 16 + l16) * 256 + ks * 32 + quad * 8];
        #pragma unroll
        for (int mt = 0; mt < 4; ++mt) {
            short8 a = *(const short8*)&sX[(mt * 16 + l16) * 264 + ks * 32 + quad * 8];
            acc[mt][0] = MFMA16(a, bfrag[0], acc[mt][0]);
            acc[mt][1] = MFMA16(a, bfrag[1], acc[mt][1]);
        }
    }

    if (mat == 0) {
        #pragma unroll
        for (int mt = 0; mt < 4; ++mt)
            #pragma unroll
            for (int ct = 0; ct < 2; ++ct) {
                int cc = c0 + ct * 16 + l16;
                float bb = bias[cc];
                #pragma unroll
                for (int r = 0; r < 4; ++r)
                    Qs[(size_t)(mtile * 64 + mt * 16 + quad * 4 + r) * 256 + cc] =
                        (acc[mt][ct][r] + bb) * 0.17677669529663687f;
            }
    } else {
        int b = mtile >> 2, j0p = (mtile & 3) * 64;
        #pragma unroll
        for (int mt = 0; mt < 4; ++mt)
            #pragma unroll
            for (int ct = 0; ct < 2; ++ct) {
                int cc = c0 + ct * 16 + l16;
                float bb = bias[cc];
                f32x4 st;
                #pragma unroll
                for (int r = 0; r < 4; ++r) st[r] = acc[mt][ct][r] + bb;
                *(f32x4*)&KT[(size_t)(b * 256 + cc) * 256 + j0p + mt * 16 + quad * 4] = st;
            }
    }
}

// ---------------------------------------------------------------------------
// V = x@Wv + bv (bf16 in LDS), then newX = V@Wxo + bxo.
// grid = 16 m-tiles (64 rows), 512 threads.
// ---------------------------------------------------------------------------
__global__ __launch_bounds__(512) void proj_vx_kernel(
    const float* __restrict__ x, const short* __restrict__ WvT,
    const float* __restrict__ bv, const short* __restrict__ WxoT,
    const float* __restrict__ bxo, float* __restrict__ outX)
{
    __shared__ unsigned short sX[64 * 264];
    __shared__ unsigned short sV[64 * 264];
    const int mtile = blockIdx.x;
    const int tid = threadIdx.x, wave = tid >> 6, lane = tid & 63;
    const int quad = lane >> 4, l16 = lane & 15;

    {
        const float4* src4 = (const float4*)(x + (size_t)mtile * 64 * XD);
        #pragma unroll
        for (int it = 0; it < 8; ++it) {
            int idx4 = tid + it * 512;
            float4 v = src4[idx4];
            int elem = idx4 * 4, row = elem >> 8, col = elem & 255;
            short4 p = make_short4((short)f2bf(v.x), (short)f2bf(v.y),
                                   (short)f2bf(v.z), (short)f2bf(v.w));
            *(short4*)&sX[row * 264 + col] = p;
        }
    }
    __syncthreads();

    const int c0 = wave * 32;
    f32x4 acc[4][2] = {};
    for (int ks = 0; ks < 8; ++ks) {
        short8 bfrag[2];
        #pragma unroll
        for (int ct = 0; ct < 2; ++ct)
            bfrag[ct] = *(const short8*)&WvT[(c0 + ct * 16 + l16) * 256 + ks * 32 + quad * 8];
        #pragma unroll
        for (int mt = 0; mt < 4; ++mt) {
            short8 a = *(const short8*)&sX[(mt * 16 + l16) * 264 + ks * 32 + quad * 8];
            acc[mt][0] = MFMA16(a, bfrag[0], acc[mt][0]);
            acc[mt][1] = MFMA16(a, bfrag[1], acc[mt][1]);
        }
    }
    #pragma unroll
    for (int mt = 0; mt < 4; ++mt)
        #pragma unroll
        for (int ct = 0; ct < 2; ++ct) {
            int cc = c0 + ct * 16 + l16;
            float bb = bv[cc];
            #pragma unroll
            for (int r = 0; r < 4; ++r)
                sV[(mt * 16 + quad * 4 + r) * 264 + cc] = f2bf(acc[mt][ct][r] + bb);
        }
    __syncthreads();

    f32x4 acc2[4][2] = {};
    for (int ks = 0; ks < 8; ++ks) {
        short8 bfrag[2];
        #pragma unroll
        for (int ct = 0; ct < 2; ++ct)
            bfrag[ct] = *(const short8*)&WxoT[(c0 + ct * 16 + l16) * 256 + ks * 32 + quad * 8];
        #pragma unroll
        for (int mt = 0; mt < 4; ++mt) {
            short8 a = *(const short8*)&sV[(mt * 16 + l16) * 264 + ks * 32 + quad * 8];
            acc2[mt][0] = MFMA16(a, bfrag[0], acc2[mt][0]);
            acc2[mt][1] = MFMA16(a, bfrag[1], acc2[mt][1]);
        }
    }
    #pragma unroll
    for (int mt = 0; mt < 4; ++mt)
        #pragma unroll
        for (int ct = 0; ct < 2; ++ct) {
            int cc = c0 + ct * 16 + l16;
            float bb = bxo[cc];
            #pragma unroll
            for (int r = 0; r < 4; ++r)
                outX[(size_t)(mtile * 64 + mt * 16 + quad * 4 + r) * 256 + cc] =
                    acc2[mt][ct][r] + bb;
        }
}

// ---------------------------------------------------------------------------
// Fused edge kernel v8 = v3 (best measured: 171.8us) + T5 s_setprio around
// MFMA clusters. 3 independent blocks/CU at uncorrelated phases -> setprio
// has waves to arbitrate (attn-positive regime, m191), zero cost otherwise.
// block = 256 thr (4 waves), tile = 64 j-rows, 4096 blocks, 52KB LDS.
// ---------------------------------------------------------------------------
__global__ __launch_bounds__(256, 3) void fused_edge_kernel(
    const float* __restrict__ e, const float* __restrict__ Qs,
    const float* __restrict__ KT, const short* __restrict__ WemT,
    const short* __restrict__ WeaT, const short* __restrict__ WeoT,
    const float* __restrict__ bem, const float* __restrict__ bea,
    const float* __restrict__ beo, float* __restrict__ outE)
{
    __shared__ unsigned short sE[64 * 140];   // e tile bf16, pitch 140
    __shared__ unsigned short sY[64 * 268];   // Y tile bf16, pitch 268

    const int blk  = blockIdx.x;              // 4096 blocks
    const int jq   = blk & 3;
    const int i    = (blk >> 2) & 255;
    const int b    = blk >> 10;
    const int j0   = jq * 64;
    const int tid  = threadIdx.x;
    const int wave = tid >> 6;
    const int lane = tid & 63;
    const int quad = lane >> 4;
    const int l16  = lane & 15;

    // ---- stage e tile [64 x 128] fp32 -> bf16 LDS
    {
        const float4* src4 = (const float4*)(e + (size_t)((b * NN + i) * NN + j0) * ED);
        #pragma unroll
        for (int it = 0; it < 8; ++it) {
            int idx4 = tid + it * 256;
            float4 v = src4[idx4];
            int elem = idx4 * 4, row = elem >> 7, col = elem & 127;
            short4 p = make_short4((short)f2bf(v.x), (short)f2bf(v.y),
                                   (short)f2bf(v.z), (short)f2bf(v.w));
            *(short4*)&sE[row * 140 + col] = p;
        }
    }

    const float* Qrow = Qs + (size_t)(b * NN + i) * XD;
    float bo[2];
    #pragma unroll
    for (int ct = 0; ct < 2; ++ct) bo[ct] = beo[wave * 32 + ct * 16 + l16];

    __syncthreads();

    // ---- GEMM1 + combine, pass-outer over column halves
    #pragma unroll
    for (int p = 0; p < 2; ++p) {
        const int c0 = wave * 32 + p * 128;
        float qsv[2], bmv[2], bav[2];
        int ktA[2];
        #pragma unroll
        for (int ct = 0; ct < 2; ++ct) {
            int cc = c0 + ct * 16 + l16;
            qsv[ct] = Qrow[cc];
            bmv[ct] = bem[cc] + 1.0f;
            bav[ct] = bea[cc];
            ktA[ct] = (b * 256 + cc) * 256 + j0 + quad * 4;
        }
        // register-resident B fragments for this pass (reused by all 4 m-chunks)
        short8 B1[4][2], B2[4][2];
        #pragma unroll
        for (int ks = 0; ks < 4; ++ks)
            #pragma unroll
            for (int ct = 0; ct < 2; ++ct) {
                int n = c0 + ct * 16 + l16;
                B1[ks][ct] = *(const short8*)&WemT[n * 128 + ks * 32 + quad * 8];
                B2[ks][ct] = *(const short8*)&WeaT[n * 128 + ks * 32 + quad * 8];
            }
        #pragma unroll
        for (int mc = 0; mc < 4; ++mc) {
            const int m0 = mc * 16;
            f32x4 aE1[2] = {}, aE2[2] = {};
            __builtin_amdgcn_s_setprio(1);
            #pragma unroll
            for (int ks = 0; ks < 4; ++ks) {
                short8 a = *(const short8*)&sE[(m0 + l16) * 140 + ks * 32 + quad * 8];
                aE1[0] = MFMA16(a, B1[ks][0], aE1[0]);
                aE1[1] = MFMA16(a, B1[ks][1], aE1[1]);
                aE2[0] = MFMA16(a, B2[ks][0], aE2[0]);
                aE2[1] = MFMA16(a, B2[ks][1], aE2[1]);
            }
            __builtin_amdgcn_s_setprio(0);
            #pragma unroll
            for (int ct = 0; ct < 2; ++ct) {
                f32x4 kv = *(const f32x4*)&KT[ktA[ct] + m0];
                int cc = c0 + ct * 16 + l16;
                #pragma unroll
                for (int r = 0; r < 4; ++r) {
                    float y = qsv[ct] * kv[r] * (aE1[ct][r] + bmv[ct])
                              + (aE2[ct][r] + bav[ct]);
                    sY[(m0 + quad * 4 + r) * 268 + cc] = f2bf(y);
                }
            }
        }
    }
    __syncthreads();

    // ---- GEMM2: newE[64 x 128] = Y @ Weo ; wave owns 32-col n-slice
    short8 B3[8][2];
    #pragma unroll
    for (int ks = 0; ks < 8; ++ks)
        #pragma unroll
        for (int ct = 0; ct < 2; ++ct)
            B3[ks][ct] = *(const short8*)&WeoT[(wave * 32 + ct * 16 + l16) * 256 + ks * 32 + quad * 8];
    f32x4 acc2[4][2] = {};
    __builtin_amdgcn_s_setprio(1);
    #pragma unroll
    for (int ks = 0; ks < 8; ++ks) {
        #pragma unroll
        for (int mt = 0; mt < 4; ++mt) {
            short8 a = *(const short8*)&sY[(mt * 16 + l16) * 268 + ks * 32 + quad * 8];
            acc2[mt][0] = MFMA16(a, B3[ks][0], acc2[mt][0]);
            acc2[mt][1] = MFMA16(a, B3[ks][1], acc2[mt][1]);
        }
    }
    __builtin_amdgcn_s_setprio(0);
    float* outBase = outE + (size_t)((b * NN + i) * NN + j0) * ED;
    #pragma unroll
    for (int mt = 0; mt < 4; ++mt)
        #pragma unroll
        for (int ct = 0; ct < 2; ++ct) {
            int col = wave * 32 + ct * 16 + l16;
            #pragma unroll
            for (int r = 0; r < 4; ++r)
                outBase[(size_t)(mt * 16 + quad * 4 + r) * ED + col] = acc2[mt][ct][r] + bo[ct];
        }
}

extern "C" void kernel_launch(void* const* d_in, const int* in_sizes, int n_in,
                              void* d_out, int out_size, void* d_ws, size_t ws_size,
                              hipStream_t stream)
{
    const float* x   = (const float*)d_in[0];
    const float* e   = (const float*)d_in[1];
    const float* Wq  = (const float*)d_in[2];
    const float* bq  = (const float*)d_in[3];
    const float* Wk  = (const float*)d_in[4];
    const float* bk  = (const float*)d_in[5];
    const float* Wv  = (const float*)d_in[6];
    const float* bv  = (const float*)d_in[7];
    const float* Wem = (const float*)d_in[8];
    const float* bem = (const float*)d_in[9];
    const float* Wea = (const float*)d_in[10];
    const float* bea = (const float*)d_in[11];
    const float* Wxo = (const float*)d_in[12];
    const float* bxo = (const float*)d_in[13];
    const float* Weo = (const float*)d_in[14];
    const float* beo = (const float*)d_in[15];

    float* outX = (float*)d_out;                 // newX: 262144 f32
    float* outE = (float*)d_out + 262144;        // newE: 33554432 f32

    float* Qs   = (float*)d_ws;                  // [1024][256] f32 (scaled)
    float* KT   = Qs + 262144;                   // [4][256 c][256 j] f32
    short* WqT  = (short*)(KT + 262144);         // [256][256] bf16
    short* WkT  = WqT + 65536;
    short* WvT  = WkT + 65536;
    short* WxoT = WvT + 65536;
    short* WemT = WxoT + 65536;                  // [256][128] bf16
    short* WeaT = WemT + 32768;
    short* WeoT = WeaT + 32768;                  // [128][256] bf16

    hipLaunchKernelGGL(wprep_kernel, dim3(352), dim3(256), 0, stream,
                       Wq, Wk, Wv, Wxo, Wem, Wea, Weo,
                       WqT, WkT, WvT, WxoT, WemT, WeaT, WeoT);
    hipLaunchKernelGGL(proj_qk_kernel, dim3(32), dim3(512), 0, stream,
                       x, WqT, WkT, bq, bk, Qs, KT);
    hipLaunchKernelGGL(proj_vx_kernel, dim3(16), dim3(512), 0, stream,
                       x, WvT, bv, WxoT, bxo, outX);
    hipLaunchKernelGGL(fused_edge_kernel, dim3(4096), dim3(256), 0, stream,
                       e, Qs, KT, WemT, WeaT, WeoT, bem, bea, beo, outE);
}